// Round 1
// baseline (72.813 us; speedup 1.0000x reference)
//
#include <hip/hip_runtime.h>

// BitLayer: y[n,b] = OR_i ( x[i,b] & (u[i,n,b] < kernel[i,n]) )
// u = jax.random.uniform(jax.random.key(42), (1024,1024,256), f32)
// Reproduce JAX Threefry-2x32 bit-exactly, with per-lane early exit on the OR.

#define INPUT_DIM 1024
#define NUM_OUTPUTS 1024
#define BIT_SIZE 256

__device__ __forceinline__ uint32_t rotl32(uint32_t v, int r) {
    return (v << r) | (v >> (32 - r));
}

// JAX threefry2x32: key (k0,k1), counter (x0,x1) -> 2 output words in-place.
__device__ __forceinline__ void threefry2x32(uint32_t k0, uint32_t k1,
                                             uint32_t& x0, uint32_t& x1) {
    const uint32_t ks0 = k0;
    const uint32_t ks1 = k1;
    const uint32_t ks2 = k0 ^ k1 ^ 0x1BD11BDAu;
    x0 += ks0;
    x1 += ks1;
#define TF_ROUND(r) { x0 += x1; x1 = rotl32(x1, (r)); x1 ^= x0; }
    TF_ROUND(13) TF_ROUND(15) TF_ROUND(26) TF_ROUND(6)
    x0 += ks1; x1 += ks2 + 1u;
    TF_ROUND(17) TF_ROUND(29) TF_ROUND(16) TF_ROUND(24)
    x0 += ks2; x1 += ks0 + 2u;
    TF_ROUND(13) TF_ROUND(15) TF_ROUND(26) TF_ROUND(6)
    x0 += ks0; x1 += ks1 + 3u;
    TF_ROUND(17) TF_ROUND(29) TF_ROUND(16) TF_ROUND(24)
    x0 += ks1; x1 += ks2 + 4u;
    TF_ROUND(13) TF_ROUND(15) TF_ROUND(26) TF_ROUND(6)
    x0 += ks2; x1 += ks0 + 5u;
#undef TF_ROUND
}

// One block per output n (1024 blocks), one thread per bit b (256 threads).
__global__ __launch_bounds__(256) void BitLayer_25391846654323_kernel(
        const int* __restrict__ x,        // (1024, 256) int32 0/1
        const float* __restrict__ kern,   // (1024, 1024) f32 probs [0,1)
        float* __restrict__ out) {        // (1024, 256) f32 0/1
    const int b = threadIdx.x;            // bit index 0..255
    const int n = blockIdx.x;             // output index 0..1023
    const uint32_t base = ((uint32_t)n << 8) | (uint32_t)b;  // n*256 + b

    float result = 0.0f;
    for (int i = 0; i < INPUT_DIM; ++i) {
        // x[i,b]: coalesced dword load per wave (64 consecutive b)
        if (x[(i << 8) + b] != 0) {
            const float p = kern[(i << 10) + n];  // block-uniform broadcast
            // linear index into u: j = i*2^18 + n*2^8 + b.  H = 2^27.
            // j <  H (i<512): bits = lane0 of threefry(counter=(j,     j+H))
            // j >= H        : bits = lane1 of threefry(counter=(j-H,   j  ))
            uint32_t c0 = (((uint32_t)(i & 511)) << 18) | base;
            uint32_t c1 = c0 + (1u << 27);
            threefry2x32(0u, 42u, c0, c1);
            const uint32_t bits = (i < 512) ? c0 : c1;
            // jax uniform f32: ((bits>>9)|0x3f800000) - 1.0 == (bits>>9)*2^-23
            const float u = (float)(bits >> 9) * 0x1p-23f;
            if (u < p) { result = 1.0f; break; }
        }
    }
    out[(n << 8) + b] = result;
}

extern "C" void kernel_launch(void* const* d_in, const int* in_sizes, int n_in,
                              void* d_out, int out_size, void* d_ws, size_t ws_size,
                              hipStream_t stream) {
    const int* x = (const int*)d_in[0];          // (1024, 256) int32
    const float* kern = (const float*)d_in[1];   // (1024, 1024) f32
    float* out = (float*)d_out;                  // (1024, 256) f32

    BitLayer_25391846654323_kernel<<<NUM_OUTPUTS, BIT_SIZE, 0, stream>>>(x, kern, out);
}

// Round 2
// 64.705 us; speedup vs baseline: 1.1253x; 1.1253x over previous
//
#include <hip/hip_runtime.h>

// BitLayer: y[n,b] = OR_i ( x[i,b] & (u[i,n,b] < kernel[i,n]) )
// u = jax.random.uniform(jax.random.key(42), (1024,1024,256), f32), threefry2x32.
//
// Structure: pack x into bitmasks (32 KB), then one block per (b, n-chunk):
//  - b block-uniform -> x-mask word is a scalar load, active-i walk wave-uniform
//  - kern[i*1024+n] coalesced across lanes (consecutive n)
//  - early exit when the whole wave has produced a 1 (__all)

#define INPUT_DIM 1024
#define NUM_OUTPUTS 1024
#define BIT_SIZE 256

__device__ __forceinline__ uint32_t rotl32(uint32_t v, int r) {
    return (v << r) | (v >> (32 - r));
}

// JAX threefry2x32: key (k0,k1), counter (x0,x1) -> 2 output words in-place.
__device__ __forceinline__ void threefry2x32(uint32_t k0, uint32_t k1,
                                             uint32_t& x0, uint32_t& x1) {
    const uint32_t ks0 = k0;
    const uint32_t ks1 = k1;
    const uint32_t ks2 = k0 ^ k1 ^ 0x1BD11BDAu;
    x0 += ks0;
    x1 += ks1;
#define TF_ROUND(r) { x0 += x1; x1 = rotl32(x1, (r)); x1 ^= x0; }
    TF_ROUND(13) TF_ROUND(15) TF_ROUND(26) TF_ROUND(6)
    x0 += ks1; x1 += ks2 + 1u;
    TF_ROUND(17) TF_ROUND(29) TF_ROUND(16) TF_ROUND(24)
    x0 += ks2; x1 += ks0 + 2u;
    TF_ROUND(13) TF_ROUND(15) TF_ROUND(26) TF_ROUND(6)
    x0 += ks0; x1 += ks1 + 3u;
    TF_ROUND(17) TF_ROUND(29) TF_ROUND(16) TF_ROUND(24)
    x0 += ks1; x1 += ks2 + 4u;
    TF_ROUND(13) TF_ROUND(15) TF_ROUND(26) TF_ROUND(6)
    x0 += ks2; x1 += ks0 + 5u;
#undef TF_ROUND
}

// Pack x (1024x256 int32 0/1) into bitmasks: xm[w*256+b] bit j = x[(w*32+j)*256+b].
// Grid 32 blocks (w) x 256 threads (b). All loads and the store are coalesced.
__global__ __launch_bounds__(256) void pack_x_kernel(const int* __restrict__ x,
                                                     uint32_t* __restrict__ xm) {
    const int b = threadIdx.x;
    const int w = blockIdx.x;  // 0..31
    uint32_t m = 0;
#pragma unroll
    for (int j = 0; j < 32; ++j) {
        m |= (x[(((w << 5) + j) << 8) + b] != 0 ? 1u : 0u) << j;
    }
    xm[(w << 8) + b] = m;
}

// Grid: 1024 blocks = 256 b x 4 n-chunks; 256 threads (consecutive n).
__global__ __launch_bounds__(256) void BitLayer_25391846654323_kernel(
        const uint32_t* __restrict__ xm,   // (32, 256) packed x
        const float* __restrict__ kern,    // (1024, 1024) f32 probs
        float* __restrict__ out) {         // (1024, 256) f32 0/1
    const int b = blockIdx.x >> 2;                                 // 0..255
    const int n = ((blockIdx.x & 3) << 8) + threadIdx.x;           // 0..1023
    uint32_t done = 0;

    for (int w = 0; w < 32; ++w) {
        uint32_t m = xm[(w << 8) + b];  // wave-uniform -> scalar load
        while (m) {
            const int j = __builtin_ctz(m);
            m &= m - 1;
            const int i = (w << 5) + j;                 // wave-uniform active input
            const float p = kern[(i << 10) + n];        // coalesced across lanes
            if (!done) {
                // linear index into u: jdx = i*2^18 + n*2^8 + b.  H = 2^27.
                // jdx <  H (i<512): bits = lane0 of threefry(counter=(jdx, jdx+H))
                // jdx >= H        : bits = lane1 of threefry(counter=(jdx-H, jdx))
                uint32_t c0 = (((uint32_t)(i & 511)) << 18) |
                              ((uint32_t)n << 8) | (uint32_t)b;
                uint32_t c1 = c0 + (1u << 27);
                threefry2x32(0u, 42u, c0, c1);
                const uint32_t bits = (i < 512) ? c0 : c1;
                // jax uniform f32: ((bits>>9)|0x3f800000) - 1.0 == (bits>>9)*2^-23
                const float u = (float)(bits >> 9) * 0x1p-23f;
                if (u < p) done = 1u;
            }
            if (__all(done != 0)) goto finished;  // whole wave satisfied -> exit
        }
    }
finished:
    out[((uint32_t)n << 8) + (uint32_t)b] = done ? 1.0f : 0.0f;
}

extern "C" void kernel_launch(void* const* d_in, const int* in_sizes, int n_in,
                              void* d_out, int out_size, void* d_ws, size_t ws_size,
                              hipStream_t stream) {
    const int* x = (const int*)d_in[0];          // (1024, 256) int32
    const float* kern = (const float*)d_in[1];   // (1024, 1024) f32
    float* out = (float*)d_out;                  // (1024, 256) f32
    uint32_t* xm = (uint32_t*)d_ws;              // 32 KB packed x bitmasks

    pack_x_kernel<<<32, 256, 0, stream>>>(x, xm);
    BitLayer_25391846654323_kernel<<<NUM_OUTPUTS, 256, 0, stream>>>(xm, kern, out);
}